// Round 1
// 1552.375 us; speedup vs baseline: 1.2888x; 1.2888x over previous
//
#include <hip/hip_runtime.h>
#include <hip/hip_bf16.h>
#include <cstdint>

typedef unsigned short u16;
typedef __bf16 bf16x8 __attribute__((ext_vector_type(8)));
typedef float floatx4 __attribute__((ext_vector_type(4)));

// ---- helpers ----------------------------------------------------------------

__device__ __forceinline__ u16 f2bf(float f) {
    union { float f; uint32_t u; } x; x.f = f;
    uint32_t u = x.u;
    u = (u + 0x7FFFu + ((u >> 16) & 1u)) >> 16;   // RNE
    return (u16)u;
}

__device__ __forceinline__ float bf2f(u16 b) {
    union { uint32_t u; float f; } x; x.u = ((uint32_t)b) << 16;
    return x.f;
}

// async global->LDS, 16B per lane; LDS dest is wave-uniform base + lane*16.
__device__ __forceinline__ void load16_to_lds(const u16* g, u16* l) {
    __builtin_amdgcn_global_load_lds(
        (const __attribute__((address_space(1))) unsigned int*)g,
        (__attribute__((address_space(3))) unsigned int*)l, 16, 0, 0);
}

// ---- pack / cast: fp32 [src_rows,src_cols] -> bf16 padded -------------------

__global__ void pack_pad(const float* __restrict__ src, u16* __restrict__ dst,
                         int src_rows, int src_cols, int pad_cols,
                         int dst_stride, int dst_off, long total) {
    long i = (long)blockIdx.x * blockDim.x + threadIdx.x;
    if (i >= total) return;
    int  col = (int)(i % pad_cols);
    long row = i / pad_cols;
    float v = (row < src_rows && col < src_cols) ? src[row * (long)src_cols + col] : 0.f;
    dst[row * (long)dst_stride + dst_off + col] = f2bf(v);
}

// ---- router: logits = x @ gate_w^T, fp32, one wave per token ----------------

__global__ void router_kernel(const float* __restrict__ x,
                              const float* __restrict__ gw,
                              float* __restrict__ out) {
    const int t = blockIdx.x;
    const int lane = threadIdx.x;            // 0..63
    const float* xr = x + (long)t * 2048;
    float acc[8] = {0.f,0.f,0.f,0.f,0.f,0.f,0.f,0.f};
    for (int k = lane; k < 2048; k += 64) {
        float xv = xr[k];
        #pragma unroll
        for (int e = 0; e < 8; e++) acc[e] += xv * gw[e * 2048 + k];
    }
    #pragma unroll
    for (int off = 32; off > 0; off >>= 1) {
        #pragma unroll
        for (int e = 0; e < 8; e++) acc[e] += __shfl_down(acc[e], off, 64);
    }
    if (lane == 0) {
        #pragma unroll
        for (int e = 0; e < 8; e++) out[(long)t * 8 + e] = acc[e];
    }
}

// ---- bf16 GEMM, 128x128 tile, BK=32, m97-style (kept for N=512 GEMMs) -------
// EPI: 0 fp32 store, 1 bf16 store, 2 bf16 silu(acc)*Mul, 3 fp32 accumulate

template <int EPI>
__global__ __launch_bounds__(256)
void gemm_bt(const u16* __restrict__ A, int lda,
             const u16* __restrict__ B, int ldb,
             void* __restrict__ C, int ldc,
             const u16* __restrict__ Mul, int ldmul,
             int K) {
    __shared__ u16 sA[128 * 32];
    __shared__ u16 sB[128 * 32];

    const int tid  = threadIdx.x;
    const int wave = tid >> 6;
    const int lane = tid & 63;
    const int l15  = lane & 15;
    const int lq   = lane >> 4;          // 0..3
    const int wm   = wave >> 1;          // 0..1
    const int wn   = wave & 1;           // 0..1
    const long rowBase = (long)blockIdx.y * 128;
    const long colBase = (long)blockIdx.x * 128;

    floatx4 acc[4][4] = {};

    const u16* gA[2]; const u16* gB[2];
    u16* lA[2]; u16* lB[2];
    #pragma unroll
    for (int i = 0; i < 2; i++) {
        int lin = i * 256 + tid;
        int row = lin >> 2;
        int kc  = lin & 3;
        gA[i] = A + (rowBase + row) * (long)lda + kc * 8;
        gB[i] = B + (colBase + row) * (long)ldb + kc * 8;
        int base = (i * 256 + wave * 64) * 8;
        lA[i] = &sA[base];
        lB[i] = &sB[base];
    }

    const int nk = K >> 5;
    for (int kt = 0; kt < nk; kt++) {
        const int ko = kt * 32;
        #pragma unroll
        for (int i = 0; i < 2; i++) {
            load16_to_lds(gA[i] + ko, lA[i]);
            load16_to_lds(gB[i] + ko, lB[i]);
        }
        __syncthreads();

        bf16x8 af[4], bb[4];
        #pragma unroll
        for (int i = 0; i < 4; i++)
            af[i] = *(const bf16x8*)&sA[(wm * 64 + i * 16 + l15) * 32 + lq * 8];
        #pragma unroll
        for (int j = 0; j < 4; j++)
            bb[j] = *(const bf16x8*)&sB[(wn * 64 + j * 16 + l15) * 32 + lq * 8];
        #pragma unroll
        for (int i = 0; i < 4; i++)
            #pragma unroll
            for (int j = 0; j < 4; j++)
                acc[i][j] = __builtin_amdgcn_mfma_f32_16x16x32_bf16(af[i], bb[j], acc[i][j], 0, 0, 0);
        __syncthreads();
    }

    #pragma unroll
    for (int i = 0; i < 4; i++) {
        long row0 = rowBase + wm * 64 + i * 16 + lq * 4;
        #pragma unroll
        for (int j = 0; j < 4; j++) {
            long col = colBase + wn * 64 + j * 16 + l15;
            #pragma unroll
            for (int r = 0; r < 4; r++) {
                float v = acc[i][j][r];
                long idx = (row0 + r) * (long)ldc + col;
                if (EPI == 0) {
                    ((float*)C)[idx] = v;
                } else if (EPI == 1) {
                    ((u16*)C)[idx] = f2bf(v);
                } else if (EPI == 2) {
                    float u = bf2f(Mul[(row0 + r) * (long)ldmul + col]);
                    float s = v / (1.f + __expf(-v));
                    ((u16*)C)[idx] = f2bf(s * u);
                } else {
                    ((float*)C)[idx] += v;
                }
            }
        }
    }
}

// ---- 256x256 8-phase bf16 GEMM (T1+T2+T3+T4+T5), C = A[M,K] @ B[N,K]^T ------
// 8 waves (2M x 4N), BK=64 staged as two 32-wide K-halves per matrix.
// LDS 128 KiB: [buf2][mat2][khalf2][256*32 elems]; linear global_load_lds dest,
// inverse-swizzled global source, swizzled ds_read (c' = c ^ ((r>>1)&3)) ->
// exactly 2-way bank access (free). Counted vmcnt(8) keeps 4 half-stages
// (8 loads) in flight across barriers; per-phase: ds_read || stage-issue ->
// barrier -> lgkmcnt(0) -> setprio(1) 16xMFMA setprio(0) -> barrier.
// Requires: M%256==0, N%256==0, K%64==0, K>=128.

template <int EPI>
__global__ __launch_bounds__(512, 2)
void gemm256(const u16* __restrict__ A, int lda,
             const u16* __restrict__ B, int ldb,
             void* __restrict__ C, int ldc,
             const u16* __restrict__ Mul, int ldmul,
             int K) {
    __shared__ __align__(16) u16 lds[65536];   // 128 KiB

    const int tid  = threadIdx.x;
    const int wave = tid >> 6;           // 0..7
    const int lane = tid & 63;
    const int l15  = lane & 15;
    const int lq   = lane >> 4;          // 0..3
    const int wm   = wave >> 2;          // 0..1
    const int wn   = wave & 3;           // 0..3

    // XCD-aware bijective block swizzle (only when nwg % 8 == 0)
    int bx = blockIdx.x, by = blockIdx.y;
    {
        int nwg = gridDim.x * gridDim.y;
        if ((nwg & 7) == 0) {
            int lin = by * gridDim.x + bx;
            int swz = (lin & 7) * (nwg >> 3) + (lin >> 3);
            bx = swz % gridDim.x;
            by = swz / gridDim.x;
        }
    }
    const long rowBase = (long)by * 256;
    const long colBase = (long)bx * 256;

    // staging source pointers: linear LDS offset o=(u*512+wave*64+lane)*16B
    // -> r = u*128 + wave*16 + (lane>>2), c = lane&3, logical c = c^((r>>1)&3)
    const u16* gA[2]; const u16* gB[2];
    int lwo[2];
    #pragma unroll
    for (int u = 0; u < 2; u++) {
        int r  = u * 128 + wave * 16 + (lane >> 2);
        int cl = (lane & 3) ^ ((r >> 1) & 3);
        gA[u] = A + (rowBase + r) * (long)lda + cl * 8;
        gB[u] = B + (colBase + r) * (long)ldb + cl * 8;
        lwo[u] = (u * 512 + wave * 64) * 8;     // elems within k-half region
    }

    // fragment-read offsets (elems). Fragment rows are multiples of 16, so the
    // swizzle XOR term reduces to a per-lane constant: (l15>>1)&3.
    const int cswz = (lq ^ ((l15 >> 1) & 3)) * 8;
    const int aoff = (wm * 128 + l15) * 32 + cswz;            // A region
    const int boff = 16384 + (wn * 64 + l15) * 32 + cswz;     // B region

    floatx4 acc[8][4] = {};

    const int nt = K >> 6;   // 64-wide K-tiles

    // stage one half-stage h (0=A-k0,1=B-k0,2=A-k1,3=B-k1) of tile kt into buf
    auto stage = [&](int buf, int h, int kt) {
        const int kh  = h >> 1;
        const int mat = h & 1;
        const long ko = (long)kt * 64 + kh * 32;
        const int base = buf * 32768 + mat * 16384 + kh * 8192;
        const u16* g0 = mat ? gB[0] : gA[0];
        const u16* g1 = mat ? gB[1] : gA[1];
        load16_to_lds(g0 + ko, &lds[base + lwo[0]]);
        load16_to_lds(g1 + ko, &lds[base + lwo[1]]);
    };

    // prologue: tile0 fully, tile1 k0-halves  (6 stages = 12 loads in flight)
    stage(0, 0, 0); stage(0, 1, 0); stage(0, 2, 0); stage(0, 3, 0);
    if (nt > 1) { stage(1, 0, 1); stage(1, 1, 1); }
    asm volatile("s_waitcnt vmcnt(8)" ::: "memory");   // tile0 k0 landed
    __builtin_amdgcn_s_barrier();

    #pragma unroll 1
    for (int t = 0; t < nt; ++t) {
        const int buf  = t & 1;
        const int bufE = buf * 32768;
        bf16x8 b[4];

        #pragma unroll
        for (int q = 0; q < 4; ++q) {
            const int ks = q >> 1;       // K-half consumed this phase
            const int mh = q & 1;        // M-half of fragments this phase
            const int rb = bufE + ks * 8192;

            // step 1: ds_read register subtile (data barriered last phase)
            if (mh == 0) {
                #pragma unroll
                for (int j = 0; j < 4; j++)
                    b[j] = *(const bf16x8*)&lds[rb + boff + j * 512];
            }
            bf16x8 a[4];
            #pragma unroll
            for (int i = 0; i < 4; i++)
                a[i] = *(const bf16x8*)&lds[rb + aoff + (mh * 4 + i) * 512];

            // step 2: issue one half-stage prefetch (stage s = 4t+q+6)
            if (q == 0)      { if (t + 1 < nt) stage(buf ^ 1, 2, t + 1); }
            else if (q == 1) { if (t + 1 < nt) stage(buf ^ 1, 3, t + 1); }
            else if (q == 2) { if (t + 2 < nt) stage(buf, 0, t + 2); }
            else             { if (t + 2 < nt) stage(buf, 1, t + 2); }

            // step 3: counted vmcnt (retire the stages the NEXT phase reads)
            if (q == 1) {
                if (t < nt - 1) { asm volatile("s_waitcnt vmcnt(8)" ::: "memory"); }
                else            { asm volatile("s_waitcnt vmcnt(0)" ::: "memory"); }
            } else if (q == 3) {
                if (t < nt - 2)       { asm volatile("s_waitcnt vmcnt(8)" ::: "memory"); }
                else if (t == nt - 2) { asm volatile("s_waitcnt vmcnt(4)" ::: "memory"); }
            }

            __builtin_amdgcn_s_barrier();
            asm volatile("s_waitcnt lgkmcnt(0)" ::: "memory");
            __builtin_amdgcn_sched_barrier(0);

            __builtin_amdgcn_s_setprio(1);
            #pragma unroll
            for (int i = 0; i < 4; i++) {
                acc[mh*4+i][0] = __builtin_amdgcn_mfma_f32_16x16x32_bf16(a[i], b[0], acc[mh*4+i][0], 0, 0, 0);
                acc[mh*4+i][1] = __builtin_amdgcn_mfma_f32_16x16x32_bf16(a[i], b[1], acc[mh*4+i][1], 0, 0, 0);
                acc[mh*4+i][2] = __builtin_amdgcn_mfma_f32_16x16x32_bf16(a[i], b[2], acc[mh*4+i][2], 0, 0, 0);
                acc[mh*4+i][3] = __builtin_amdgcn_mfma_f32_16x16x32_bf16(a[i], b[3], acc[mh*4+i][3], 0, 0, 0);
            }
            __builtin_amdgcn_s_setprio(0);
            __builtin_amdgcn_s_barrier();
        }
    }

    // epilogue: C/D layout col = lane&15, row = (lane>>4)*4 + reg
    #pragma unroll
    for (int f = 0; f < 8; f++) {
        long row0 = rowBase + wm * 128 + f * 16 + lq * 4;
        #pragma unroll
        for (int j = 0; j < 4; j++) {
            long col = colBase + wn * 64 + j * 16 + l15;
            #pragma unroll
            for (int r = 0; r < 4; r++) {
                float v = acc[f][j][r];
                long idx = (row0 + r) * (long)ldc + col;
                if (EPI == 0) {
                    ((float*)C)[idx] = v;
                } else if (EPI == 1) {
                    ((u16*)C)[idx] = f2bf(v);
                } else if (EPI == 2) {
                    float u = bf2f(Mul[(row0 + r) * (long)ldmul + col]);
                    float s = v / (1.f + __expf(-v));
                    ((u16*)C)[idx] = f2bf(s * u);
                } else {
                    ((float*)C)[idx] += v;
                }
            }
        }
    }
}

// ---- launch -----------------------------------------------------------------

static inline void launch_pack(const float* src, u16* dst, int sr, int sc,
                               int pr, int pc, int stride, int off,
                               hipStream_t stream) {
    long total = (long)pr * pc;
    int blocks = (int)((total + 255) / 256);
    hipLaunchKernelGGL(pack_pad, dim3(blocks), dim3(256), 0, stream,
                       src, dst, sr, sc, pc, stride, off, total);
}

extern "C" void kernel_launch(void* const* d_in, const int* in_sizes, int n_in,
                              void* d_out, int out_size, void* d_ws, size_t ws_size,
                              hipStream_t stream) {
    const float* x      = (const float*)d_in[0];   // [8192, 2048]
    const float* gate_w = (const float*)d_in[1];   // [8, 2048]
    const float* w1     = (const float*)d_in[2];   // [7168, 2048]
    const float* w2     = (const float*)d_in[3];   // [2048, 7168]
    const float* w3     = (const float*)d_in[4];   // [7168, 2048]
    const float* u1     = (const float*)d_in[5];   // [7168, 398]
    const float* v1     = (const float*)d_in[6];   // [398, 2048]
    const float* u2     = (const float*)d_in[7];   // [2048, 398]
    const float* v2     = (const float*)d_in[8];   // [398, 7168]
    const float* u3     = (const float*)d_in[9];   // [7168, 398]
    const float* v3     = (const float*)d_in[10];  // [398, 2048]

    float* out    = (float*)d_out;                 // [8192,2048] then [8192,8]
    float* logits = out + 16777216L;

    // ---- workspace layout (bf16 elems) ----
    u16* XT = (u16*)d_ws;                  // [8192,3072] = [T3 | Xb | T1]
    u16* WR = XT + 25165824L;              // shared weight region (phased)
    u16* UB = WR + 19398656L;              // [8192,7168] up, then H in-place
    u16* T2 = XT;                          // [8192,512] after GEMM3 (XT dead)

    u16* V3P = WR;
    u16* V1P = WR + 512L * 2048;
    u16* WU  = WR;                         // [7168,2560] = [u3p | w3]
    u16* WG  = WR;                         // [7168,2560] = [w1 | u1p]
    u16* V2P = WR;                         // [512,7168]
    u16* W2B = WR + 512L * 7168;           // [2048,7168]
    u16* U2P = W2B + 2048L * 7168;         // [2048,512]

    // ---- router ----
    hipLaunchKernelGGL(router_kernel, dim3(8192), dim3(64), 0, stream,
                       x, gate_w, logits);

    // ---- pack phase A ----
    launch_pack(x,  XT + 512, 8192, 2048, 8192, 2048, 3072, 0, stream);  // Xb
    launch_pack(v3, V3P, 398, 2048, 512, 2048, 2048, 0, stream);
    launch_pack(v1, V1P, 398, 2048, 512, 2048, 2048, 0, stream);

    // ---- GEMM1a: T3 = Xb @ v3p^T  (N=512: keep 128^2 kernel) ----
    hipLaunchKernelGGL((gemm_bt<1>), dim3(4, 64), dim3(256), 0, stream,
                       XT + 512, 3072, V3P, 2048, (void*)XT, 3072,
                       (const u16*)nullptr, 0, 2048);
    // ---- GEMM1b: T1 = Xb @ v1p^T ----
    hipLaunchKernelGGL((gemm_bt<1>), dim3(4, 64), dim3(256), 0, stream,
                       XT + 512, 3072, V1P, 2048, (void*)(XT + 2560), 3072,
                       (const u16*)nullptr, 0, 2048);

    // ---- pack phase B: WU = [u3p | w3] ----
    launch_pack(u3, WU, 7168, 398, 7168, 512, 2560, 0, stream);
    launch_pack(w3, WU, 7168, 2048, 7168, 2048, 2560, 512, stream);

    // ---- GEMM2: UB = XT[:,0:2560] @ WU^T  (256^2 8-phase) ----
    hipLaunchKernelGGL((gemm256<1>), dim3(28, 32), dim3(512), 0, stream,
                       XT, 3072, WU, 2560, (void*)UB, 7168,
                       (const u16*)nullptr, 0, 2560);

    // ---- pack phase C: WG = [w1 | u1p] ----
    launch_pack(w1, WG, 7168, 2048, 7168, 2048, 2560, 0, stream);
    launch_pack(u1, WG, 7168, 398, 7168, 512, 2560, 2048, stream);

    // ---- GEMM3: UB = silu(XT[:,512:3072] @ WG^T) * UB  (in-place) ----
    hipLaunchKernelGGL((gemm256<2>), dim3(28, 32), dim3(512), 0, stream,
                       XT + 512, 3072, WG, 2560, (void*)UB, 7168,
                       UB, 7168, 2560);

    // ---- pack phase D: {v2p, w2b, u2p} ----
    launch_pack(v2, V2P, 398, 7168, 512, 7168, 7168, 0, stream);
    launch_pack(w2, W2B, 2048, 7168, 2048, 7168, 7168, 0, stream);
    launch_pack(u2, U2P, 2048, 398, 2048, 512, 512, 0, stream);

    // ---- GEMM4: T2 = H @ v2p^T  (N=512: keep 128^2 kernel) ----
    hipLaunchKernelGGL((gemm_bt<1>), dim3(4, 64), dim3(256), 0, stream,
                       UB, 7168, V2P, 7168, (void*)T2, 512,
                       (const u16*)nullptr, 0, 7168);

    // ---- GEMM5a: out = H @ w2b^T (fp32 store, 256^2 8-phase) ----
    hipLaunchKernelGGL((gemm256<0>), dim3(8, 32), dim3(512), 0, stream,
                       UB, 7168, W2B, 7168, (void*)out, 2048,
                       (const u16*)nullptr, 0, 7168);

    // ---- GEMM5b: out += T2 @ u2p^T (fp32 accumulate) ----
    hipLaunchKernelGGL((gemm256<3>), dim3(8, 32), dim3(512), 0, stream,
                       T2, 512, U2P, 512, (void*)out, 2048,
                       (const u16*)nullptr, 0, 512);
}